// Round 7
// baseline (184.452 us; speedup 1.0000x reference)
//
#include <hip/hip_runtime.h>
#include <math.h>

// Problem constants
#define BN 256
#define TN 64
#define LN 32
#define DN 128
#define SN 4
#define HN 32   // column-panel width for the blocked elimination

#define LOG2PI 1.8378770664093453f

__device__ __forceinline__ float bcastf(float v, int lane) {
    return __builtin_bit_cast(float, __builtin_amdgcn_readlane(__builtin_bit_cast(int, v), lane));
}

// ===========================================================================
// Lessons R1-R6:
//  * >64 live floats/lane => allocator parks overflow in AGPRs (VGPR_Count
//    pinned at 64, accvgpr shuffling, 2-3x VALU inflation). Occupancy
//    attributes never changed it. Fix is structural: <=~47 live floats via
//    32-wide column panels + LDS c-panel replay.
//  * All per-lane array subscripts must be frontend-time constants
//    (recursive if-constexpr templates) or SROA demotes to scratch.
//  * R6 NaN: 16 full 64x64 matrices = 278 KB cannot fit LDS. Block now
//    holds 4 matrices (69.7 KB) -> 2 blocks/CU, stage/compute overlap.
// ===========================================================================

// ======================== k_kinv (blocked Gauss-Jordan) ====================
// One wave per l. Lane i = row i. Panels of 32 cols; multipliers c_i^{(K)}
// stored to an LDS c-panel (cp[i*65+K], 2-way banks); logdet from pivots;
// inverse halves reconstructed by replaying the c-panel onto I.
#define CPIDX(i, K) ((i) * 65 + (K))

template<int J>
__device__ __forceinline__ void pan_load(float (&p)[HN], const float* __restrict__ Kmat,
                                         int i, int l, int jbase) {
    if constexpr (J < HN) {
        p[J] = Kmat[(i * TN + jbase + J) * LN + l];
        pan_load<J + 1>(p, Kmat, i, l, jbase);
    }
}
// sweep K=0..31 on left panel (cols 0..31); G-J: all rows i!=K updated
template<int K, int J>
__device__ __forceinline__ void a1_upd(float (&a1)[HN], float c) {
    if constexpr (J < HN) {
        a1[J] = fmaf(-c, bcastf(a1[J], K), a1[J]);
        a1_upd<K, J + 1>(a1, c);
    }
}
template<int K>
__device__ __forceinline__ void a1_sweep(float (&a1)[HN], float& ld, float& piv,
                                         int i, float* cp) {
    if constexpr (K < HN) {
        float dkk = bcastf(a1[K], K);
        ld += __logf(dkk);
        if (i == K) piv = dkk;
        float c = (i == K) ? 0.0f : a1[K] * __builtin_amdgcn_rcpf(dkk);
        cp[CPIDX(i, K)] = c;
        a1_upd<K, K + 1>(a1, c);
        a1_sweep<K + 1>(a1, ld, piv, i, cp);
    }
}
// replay steps 0..31 onto right panel (cols 32..63); row K preserved in G-J
template<int K, int J>
__device__ __forceinline__ void a2_rep_upd(float (&a2)[HN], float c) {
    if constexpr (J < HN) {
        a2[J] = fmaf(-c, bcastf(a2[J], K), a2[J]);
        a2_rep_upd<K, J + 1>(a2, c);
    }
}
template<int K>
__device__ __forceinline__ void a2_replay(float (&a2)[HN], const float* cp, int i) {
    if constexpr (K < HN) {
        float c = cp[CPIDX(i, K)];
        a2_rep_upd<K, 0>(a2, c);
        a2_replay<K + 1>(a2, cp, i);
    }
}
// sweep K=32..63 (Q=K-32) on right panel
template<int Q, int J>
__device__ __forceinline__ void a2_upd(float (&a2)[HN], float c) {
    if constexpr (J < HN) {
        a2[J] = fmaf(-c, bcastf(a2[J], 32 + Q), a2[J]);
        a2_upd<Q, J + 1>(a2, c);
    }
}
template<int Q>
__device__ __forceinline__ void a2_sweep(float (&a2)[HN], float& ld, float& piv,
                                         int i, float* cp) {
    if constexpr (Q < HN) {
        float dkk = bcastf(a2[Q], 32 + Q);
        ld += __logf(dkk);
        if (i == 32 + Q) piv = dkk;
        float c = (i == 32 + Q) ? 0.0f : a2[Q] * __builtin_amdgcn_rcpf(dkk);
        cp[CPIDX(i, 32 + Q)] = c;
        a2_upd<Q, Q + 1>(a2, c);
        a2_sweep<Q + 1>(a2, ld, piv, i, cp);
    }
}
// G reconstruction, left half (cols 0..31): row K of G has nonzero cols <= K
template<int J>
__device__ __forceinline__ void g1_init(float (&g)[HN], int i) {
    if constexpr (J < HN) { g[J] = (J == i) ? 1.0f : 0.0f; g1_init<J + 1>(g, i); }
}
template<int K, int J>
__device__ __forceinline__ void g1_updA(float (&g)[HN], float c) {
    if constexpr (J <= K) {
        g[J] = fmaf(-c, bcastf(g[J], K), g[J]);
        g1_updA<K, J + 1>(g, c);
    }
}
template<int K>
__device__ __forceinline__ void g1_phase1(float (&g)[HN], const float* cp, int i) {
    if constexpr (K < HN) {
        float c = cp[CPIDX(i, K)];
        g1_updA<K, 0>(g, c);
        g1_phase1<K + 1>(g, cp, i);
    }
}
template<int K, int J>
__device__ __forceinline__ void g1_updB(float (&g)[HN], float c) {
    if constexpr (J < HN) {
        g[J] = fmaf(-c, bcastf(g[J], K), g[J]);
        g1_updB<K, J + 1>(g, c);
    }
}
template<int Q>
__device__ __forceinline__ void g1_phase2(float (&g)[HN], const float* cp, int i) {
    if constexpr (Q < HN) {
        float c = cp[CPIDX(i, 32 + Q)];
        g1_updB<32 + Q, 0>(g, c);
        g1_phase2<Q + 1>(g, cp, i);
    }
}
// G right half (cols 32..63): only steps K>=32 touch these cols; cols <= K
template<int J>
__device__ __forceinline__ void g2_init(float (&g)[HN], int i) {
    if constexpr (J < HN) { g[J] = (32 + J == i) ? 1.0f : 0.0f; g2_init<J + 1>(g, i); }
}
template<int Q, int J>
__device__ __forceinline__ void g2_upd(float (&g)[HN], float c) {
    if constexpr (J <= Q) {
        g[J] = fmaf(-c, bcastf(g[J], 32 + Q), g[J]);
        g2_upd<Q, J + 1>(g, c);
    }
}
template<int Q>
__device__ __forceinline__ void g2_phase(float (&g)[HN], const float* cp, int i) {
    if constexpr (Q < HN) {
        float c = cp[CPIDX(i, 32 + Q)];
        g2_upd<Q, 0>(g, c);
        g2_phase<Q + 1>(g, cp, i);
    }
}
template<int J>
__device__ __forceinline__ void pan_out(const float (&g)[HN], float rdi,
                                        float* __restrict__ dst) {
    if constexpr (J < HN) {
        dst[J] = g[J] * rdi;
        pan_out<J + 1>(g, rdi, dst);
    }
}

__global__ __launch_bounds__(64)
void k_kinv(const float* __restrict__ Kmat,
            float* __restrict__ kinv,
            float* __restrict__ logdetK) {
    __shared__ float cp[TN * 65];   // c-panel: 16.6 KB, (i+K)%32 banks -> 2-way
    const int l = blockIdx.x;
    const int i = threadIdx.x;      // row

    float ld = 0.0f, piv = 1.0f;
    {
        float a1[HN];
        pan_load<0>(a1, Kmat, i, l, 0);
        a1_sweep<0>(a1, ld, piv, i, cp);
    }
    {
        float a2[HN];
        pan_load<0>(a2, Kmat, i, l, 32);
        a2_replay<0>(a2, cp, i);
        a2_sweep<0>(a2, ld, piv, i, cp);
    }
    float rdi = __builtin_amdgcn_rcpf(piv);
    {
        float g1[HN];
        g1_init<0>(g1, i);
        g1_phase1<0>(g1, cp, i);
        g1_phase2<0>(g1, cp, i);
        pan_out<0>(g1, rdi, kinv + l * (TN * TN) + i * TN);
    }
    {
        float g2[HN];
        g2_init<0>(g2, i);
        g2_phase<0>(g2, cp, i);
        pan_out<0>(g2, rdi, kinv + l * (TN * TN) + i * TN + 32);
    }
    if (i == 0) logdetK[l] = ld;
}

// ---------------------------------------------------------------------------
// Kernel 2: log-likelihood streaming part (unchanged, known-correct).
// ---------------------------------------------------------------------------
__global__ void __launch_bounds__(256) k_ll(const float* __restrict__ X,
                                            const float* __restrict__ Mn,
                                            const float* __restrict__ R,
                                            float* __restrict__ out) {
    int hw = blockIdx.x;                 // 1024 blocks
    int g = (hw & 7) * 128 + (hw >> 3);
    int b = g >> 2, s = g & 3;
    int tid = threadIdx.x;

    const float4* xp = (const float4*)(X + (size_t)b * TN * DN);
    const float4* mp = (const float4*)(Mn + ((size_t)(b * SN + s) * TN) * DN);

    int c = tid & 31;
    float4 rv = ((const float4*)R)[c];
    float4 ri = make_float4(1.0f / rv.x, 1.0f / rv.y, 1.0f / rv.z, 1.0f / rv.w);

    float acc = 0.0f;
#pragma unroll
    for (int it = 0; it < (TN * DN / 4) / 256; ++it) {
        int f = tid + it * 256;
        float4 xv = xp[f];
        float4 mv = mp[f];
        float dx = xv.x - mv.x; acc = fmaf(dx * dx, ri.x, acc);
        float dy = xv.y - mv.y; acc = fmaf(dy * dy, ri.y, acc);
        float dz = xv.z - mv.z; acc = fmaf(dz * dz, ri.z, acc);
        float dw = xv.w - mv.w; acc = fmaf(dw * dw, ri.w, acc);
    }
#pragma unroll
    for (int off = 32; off >= 1; off >>= 1) acc += __shfl_xor(acc, off, 64);

    __shared__ float wsum[4];
    if ((tid & 63) == 0) wsum[tid >> 6] = acc;
    __syncthreads();
    if (tid == 0) {
        float q = wsum[0] + wsum[1] + wsum[2] + wsum[3];
        float val = q * (0.5f / SN);
        if (s == 0) {
            float slr = 0.0f;
#pragma unroll
            for (int d = 0; d < DN; ++d) slr += __logf(R[d]);
            val += 0.5f * (float)TN * (slr + (float)DN * LOG2PI);
        }
        atomicAdd(&out[b], val);
    }
}

// ======================== k_chol (blocked elimination) =====================
template<int OFF, int J4>
__device__ __forceinline__ void fill32(float (&r)[HN], const float4* rp) {
    if constexpr (J4 < 8) {
        float4 v = rp[OFF + J4];
        r[4 * J4 + 0] = v.x; r[4 * J4 + 1] = v.y;
        r[4 * J4 + 2] = v.z; r[4 * J4 + 3] = v.w;
        fill32<OFF, J4 + 1>(r, rp);
    }
}
template<int JBASE, int J4>
__device__ __forceinline__ void trace_half(const float (&r)[HN], const float* __restrict__ kp,
                                           float mu, float& tr, float& sm) {
    if constexpr (J4 < 8) {
        float4 kv = *(const float4*)(kp + 4 * J4);
        tr = fmaf(kv.x, r[4 * J4 + 0], tr); sm = fmaf(kv.x, bcastf(mu, JBASE + 4 * J4 + 0), sm);
        tr = fmaf(kv.y, r[4 * J4 + 1], tr); sm = fmaf(kv.y, bcastf(mu, JBASE + 4 * J4 + 1), sm);
        tr = fmaf(kv.z, r[4 * J4 + 2], tr); sm = fmaf(kv.z, bcastf(mu, JBASE + 4 * J4 + 2), sm);
        tr = fmaf(kv.w, r[4 * J4 + 3], tr); sm = fmaf(kv.w, bcastf(mu, JBASE + 4 * J4 + 3), sm);
        trace_half<JBASE, J4 + 1>(r, kp, mu, tr, sm);
    }
}
// pivots 0..31 on cols 0..31 (symmetric trailing read: A[K][J] = lane J's r1[K])
template<int K, int J>
__device__ __forceinline__ void c1_upd(float (&r1)[HN], float c) {
    if constexpr (J < HN) {
        r1[J] = fmaf(-c, bcastf(r1[K], J), r1[J]);
        c1_upd<K, J + 1>(r1, c);
    }
}
template<int K>
__device__ __forceinline__ void c1_sweep(float (&r1)[HN], float& logdet, float* cpan, int lane) {
    if constexpr (K < HN) {
        float dkk = bcastf(r1[K], K);
        logdet += __logf(dkk);
        float c = r1[K] * __builtin_amdgcn_rcpf(dkk);
        cpan[(K + lane) & 31] = c;       // lane-private slot, bank-swizzled (2-way)
        c1_upd<K, K + 1>(r1, c);
        c1_sweep<K + 1>(r1, logdet, cpan, lane);
    }
}
// replay pivots 0..31 onto cols 32..63: row K's right half = lane K's r2
// (exact through step K; self-zeroing with c=1 happens after the in-instr read)
template<int K, int J>
__device__ __forceinline__ void rep_upd(float (&r2)[HN], float c) {
    if constexpr (J < HN) {
        r2[J] = fmaf(-c, bcastf(r2[J], K), r2[J]);
        rep_upd<K, J + 1>(r2, c);
    }
}
template<int K>
__device__ __forceinline__ void rep_sweep(float (&r2)[HN], const float* cpan, int lane) {
    if constexpr (K < HN) {
        float c = cpan[(K + lane) & 31];
        rep_upd<K, 0>(r2, c);
        rep_sweep<K + 1>(r2, cpan, lane);
    }
}
// pivots 32..63 on trailing 32x32 (lanes 32..63 hold valid rows)
template<int Q, int J>
__device__ __forceinline__ void solo_upd(float (&r2)[HN], float c) {
    if constexpr (J < HN) {
        r2[J] = fmaf(-c, bcastf(r2[Q], 32 + J), r2[J]);
        solo_upd<Q, J + 1>(r2, c);
    }
}
template<int Q>
__device__ __forceinline__ void solo_sweep(float (&r2)[HN], float& logdet) {
    if constexpr (Q < HN) {
        float dkk = bcastf(r2[Q], 32 + Q);
        logdet += __logf(dkk);
        float c = r2[Q] * __builtin_amdgcn_rcpf(dkk);
        solo_upd<Q, Q + 1>(r2, c);
        solo_sweep<Q + 1>(r2, logdet);
    }
}

// Block = 256 threads = 4 waves = one (b, l-quad). LDS holds the 4 full
// matrices (69.7 KB) -> 2 blocks/CU, staging overlaps compute across blocks.
// Swizzle puts the 8 sibling l-quads of one b on one XCD (shared Sg lines).
#define LSTR 68                  // row stride (floats), 272 B = 17 granules
#define PL4  (TN * LSTR + 4)     // per-l plane stride = 4356 floats

__global__ __launch_bounds__(256)
void k_chol(const float* __restrict__ Sg,
            const float* __restrict__ mus,
            const float* __restrict__ kinv,
            const float* __restrict__ logdetK,
            float* __restrict__ out) {
    __shared__ float st[4 * PL4];  // 69.7 KB

    int hw = blockIdx.x;                 // 2048 blocks
    int g = (hw & 7) * 256 + (hw >> 3);  // XCD x owns b in [x*32, x*32+32)
    int b = g >> 3, lg = g & 7;          // lg = l-quad 0..7

    int tid = threadIdx.x;
    int w = tid >> 6, lane = tid & 63;   // wave w <-> l = lg*4 + w; lane = row
    int l = lg * 4 + w;

    // stage 4 matrices: element (i,j) of l-quad = one float4 over l
#pragma unroll
    for (int it = 0; it < 16; ++it) {
        int m = tid + it * 256;          // 0..4095
        int j = m & 63;
        int i = m >> 6;
        const float* gp = Sg + ((((size_t)b * TN + i) * TN + j) * LN + lg * 4);
        float4 v = *(const float4*)gp;
        st[0 * PL4 + i * LSTR + j] = v.x;
        st[1 * PL4 + i * LSTR + j] = v.y;
        st[2 * PL4 + i * LSTR + j] = v.z;
        st[3 * PL4 + i * LSTR + j] = v.w;
    }
    __syncthreads();

    float* rowp = &st[w * PL4 + lane * LSTR];   // this lane's matrix row
    float mu = mus[((size_t)b * TN + lane) * LN + l];
    const float* kp = kinv + l * (TN * TN) + lane * TN;

    float tr = 0.0f, sm = 0.0f, logdet = 0.0f;

    {
        float r1[HN];
        fill32<0, 0>(r1, (const float4*)rowp);     // cols 0..31
        trace_half<0, 0>(r1, kp, mu, tr, sm);
        c1_sweep<0>(r1, logdet, rowp, lane);       // c-panel -> dead left half
    }
    {
        float r2[HN];
        fill32<8, 0>(r2, (const float4*)rowp);     // cols 32..63 (untouched)
        trace_half<32, 0>(r2, kp + 32, mu, tr, sm);
        rep_sweep<0>(r2, rowp, lane);              // deferred right-half updates
        solo_sweep<0>(r2, logdet);                 // trailing 32x32 pivots
    }

    float contrib = tr + mu * sm;
#pragma unroll
    for (int off = 32; off >= 1; off >>= 1) contrib += __shfl_xor(contrib, off, 64);

    if (lane == 0) {
        float klp = 0.5f * (logdetK[l] - logdet - (float)TN + contrib);
        atomicAdd(&out[b], klp);
    }
}

// ---------------------------------------------------------------------------
extern "C" void kernel_launch(void* const* d_in, const int* in_sizes, int n_in,
                              void* d_out, int out_size, void* d_ws, size_t ws_size,
                              hipStream_t stream) {
    const float* X   = (const float*)d_in[0];  // [B,T,D]
    const float* Mn  = (const float*)d_in[1];  // [B,S,T,D]
    const float* R   = (const float*)d_in[2];  // [D]
    const float* mus = (const float*)d_in[3];  // [B,T,L]
    const float* Sg  = (const float*)d_in[4];  // [B,T,T,L]
    const float* Km  = (const float*)d_in[5];  // [T,T,L]
    float* out = (float*)d_out;                // [B] fp32

    float* kinv = (float*)d_ws;                // 32*4096 floats = 512 KB
    float* ldK  = kinv + LN * TN * TN;         // 32 floats

    hipMemsetAsync(d_out, 0, BN * sizeof(float), stream);
    k_kinv<<<LN, 64, 0, stream>>>(Km, kinv, ldK);
    k_ll<<<BN * SN, 256, 0, stream>>>(X, Mn, R, out);
    k_chol<<<BN * 8, 256, 0, stream>>>(Sg, mus, kinv, ldK, out);
}

// Round 8
// 144.149 us; speedup vs baseline: 1.2796x; 1.2796x over previous
//
#include <hip/hip_runtime.h>
#include <math.h>

// Problem constants
#define BN 256
#define TN 64
#define LN 32
#define DN 128
#define SN 4
#define HN 32   // column-panel width for the blocked elimination

#define LOG2PI 1.8378770664093453f

__device__ __forceinline__ float bcastf(float v, int lane) {
    return __builtin_bit_cast(float, __builtin_amdgcn_readlane(__builtin_bit_cast(int, v), lane));
}

// ===========================================================================
// Lessons R1-R7:
//  * All per-lane array subscripts must be frontend-time constants
//    (recursive if-constexpr templates) or SROA demotes to scratch.
//  * >64 live floats/lane -> AGPR parking (R5). Keep <=~50 live: 32-wide
//    panels. R7: with <=47 live the allocator used 88 real VGPRs, no spill.
//  * R7 residual: 70KB LDS -> 2 blocks/CU -> 2 waves/SIMD -> readlane->fma
//    chains exposed (VALUBusy 45%, 10cyc/instr). This round: 32KB LDS
//    (panel staging, swizzled banks) + multipliers stored in DEAD register
//    slots (r1[K] dead after step K) -> zero LDS in the sweeps.
// ===========================================================================

// LDS plane layout: [64 rows][8 chunks][4 dwords]; chunk q of row i lives at
// position (q + i + (i>>3)) & 7. Rows i and i+8 share a bank-base (any 16B
// aligned stride does); the i>>3 term gives them different chunk positions,
// so the 8 rows aliasing each bank-base hit 8 distinct 16B slots.
__device__ __forceinline__ int chunk_pos(int q, int i) { return (q + i + (i >> 3)) & 7; }

// ---- shared template helpers ---------------------------------------------
template<int Q>
__device__ __forceinline__ void fillp(float (&r)[HN], const float* plane, int l) {
    if constexpr (Q < 8) {
        const float4 v = *(const float4*)(plane + l * 32 + chunk_pos(Q, l) * 4);
        r[4 * Q + 0] = v.x; r[4 * Q + 1] = v.y;
        r[4 * Q + 2] = v.z; r[4 * Q + 3] = v.w;
        fillp<Q + 1>(r, plane, l);
    }
}
template<int JBASE, int J4>
__device__ __forceinline__ void trace_half(const float (&r)[HN], const float* __restrict__ kp,
                                           float mu, float& tr, float& sm) {
    if constexpr (J4 < 8) {
        float4 kv = *(const float4*)(kp + 4 * J4);
        tr = fmaf(kv.x, r[4 * J4 + 0], tr); sm = fmaf(kv.x, bcastf(mu, JBASE + 4 * J4 + 0), sm);
        tr = fmaf(kv.y, r[4 * J4 + 1], tr); sm = fmaf(kv.y, bcastf(mu, JBASE + 4 * J4 + 1), sm);
        tr = fmaf(kv.z, r[4 * J4 + 2], tr); sm = fmaf(kv.z, bcastf(mu, JBASE + 4 * J4 + 2), sm);
        tr = fmaf(kv.w, r[4 * J4 + 3], tr); sm = fmaf(kv.w, bcastf(mu, JBASE + 4 * J4 + 3), sm);
        trace_half<JBASE, J4 + 1>(r, kp, mu, tr, sm);
    }
}

// ---- k_chol sweeps (register-resident multipliers) -----------------------
// pivots 0..31 on cols 0..31; symmetric trailing read: A[K][J] = lane J's r1[K].
// After step K's updates, r1[K] is dead in every lane -> store c there
// (lockstep: all cross-lane reads of step K precede the overwrite).
template<int K, int J>
__device__ __forceinline__ void c1_upd(float (&r1)[HN], float c) {
    if constexpr (J < HN) {
        r1[J] = fmaf(-c, bcastf(r1[K], J), r1[J]);
        c1_upd<K, J + 1>(r1, c);
    }
}
template<int K>
__device__ __forceinline__ void c1_sweep(float (&r1)[HN], float& logdet) {
    if constexpr (K < HN) {
        float dkk = bcastf(r1[K], K);
        logdet += __logf(dkk);
        float c = r1[K] * __builtin_amdgcn_rcpf(dkk);
        c1_upd<K, K + 1>(r1, c);
        r1[K] = c;                          // multiplier -> dead slot
        c1_sweep<K + 1>(r1, logdet);
    }
}
// replay pivots 0..31 onto cols 32..63; pivot row K's right half = lane K's
// r2 (exact through step K; its self-update happens after the bcast read).
template<int K, int J>
__device__ __forceinline__ void rep_upd(float (&r2)[HN], float c) {
    if constexpr (J < HN) {
        r2[J] = fmaf(-c, bcastf(r2[J], K), r2[J]);
        rep_upd<K, J + 1>(r2, c);
    }
}
template<int K>
__device__ __forceinline__ void rep_sweep(float (&r2)[HN], const float (&r1)[HN]) {
    if constexpr (K < HN) {
        rep_upd<K, 0>(r2, r1[K]);           // c from own stored multiplier
        rep_sweep<K + 1>(r2, r1);
    }
}
// pivots 32..63 on trailing 32x32 (lanes 32..63 hold the Schur rows)
template<int Q, int J>
__device__ __forceinline__ void solo_upd(float (&r2)[HN], float c) {
    if constexpr (J < HN) {
        r2[J] = fmaf(-c, bcastf(r2[Q], 32 + J), r2[J]);
        solo_upd<Q, J + 1>(r2, c);
    }
}
template<int Q>
__device__ __forceinline__ void solo_sweep(float (&r2)[HN], float& logdet) {
    if constexpr (Q < HN) {
        float dkk = bcastf(r2[Q], 32 + Q);
        logdet += __logf(dkk);
        float c = r2[Q] * __builtin_amdgcn_rcpf(dkk);
        solo_upd<Q, Q + 1>(r2, c);
        solo_sweep<Q + 1>(r2, logdet);
    }
}

// ---------------------------------------------------------------------------
// Kernel: k_chol. Block = 256 threads = 4 waves = one (b, l-quad).
// LDS = 4 planes x 64x32 panel = 32 KB, reused for panel1 -> panel2.
// ---------------------------------------------------------------------------
__global__ __launch_bounds__(256)
void k_chol(const float* __restrict__ Sg,
            const float* __restrict__ mus,
            const float* __restrict__ kinv,
            const float* __restrict__ logdetK,
            float* __restrict__ out) {
    __shared__ float st[4 * 2048];       // 32 KB

    int hw = blockIdx.x;                 // 2048 blocks
    int g = (hw & 7) * 256 + (hw >> 3);  // XCD x owns b in [x*32, x*32+32)
    int b = g >> 3, lg = g & 7;          // lg = l-quad 0..7

    int tid = threadIdx.x;
    int w = tid >> 6, lane = tid & 63;   // wave w <-> l = lg*4 + w; lane = row
    int l = lg * 4 + w;

    float mu = mus[((size_t)b * TN + lane) * LN + l];
    const float* kp = kinv + l * (TN * TN) + lane * TN;
    const float* plane = &st[w * 2048];

    // ---- stage panel 1 (cols 0..31) ----
#pragma unroll
    for (int it = 0; it < 8; ++it) {
        int m = tid + it * 256;          // 0..2047
        int j = m & 31, i = m >> 5;
        const float* gp = Sg + ((((size_t)b * TN + i) * TN + j) * LN + lg * 4);
        float4 v = *(const float4*)gp;
        int off = i * 32 + chunk_pos(j >> 2, i) * 4 + (j & 3);
        st[0 * 2048 + off] = v.x;
        st[1 * 2048 + off] = v.y;
        st[2 * 2048 + off] = v.z;
        st[3 * 2048 + off] = v.w;
    }
    __syncthreads();

    float r1[HN];
    fillp<0>(r1, plane, lane);           // cols 0..31 into registers
    __syncthreads();                     // all waves done reading panel1

    // ---- stage panel 2 (cols 32..63) over panel1's LDS ----
#pragma unroll
    for (int it = 0; it < 8; ++it) {
        int m = tid + it * 256;
        int j = m & 31, i = m >> 5;
        const float* gp = Sg + ((((size_t)b * TN + i) * TN + 32 + j) * LN + lg * 4);
        float4 v = *(const float4*)gp;
        int off = i * 32 + chunk_pos(j >> 2, i) * 4 + (j & 3);
        st[0 * 2048 + off] = v.x;
        st[1 * 2048 + off] = v.y;
        st[2 * 2048 + off] = v.z;
        st[3 * 2048 + off] = v.w;
    }
    __syncthreads();                     // last barrier; pure compute below

    float tr = 0.0f, sm = 0.0f, logdet = 0.0f;
    trace_half<0, 0>(r1, kp, mu, tr, sm);
    c1_sweep<0>(r1, logdet);             // r1 now holds multipliers c_0..31

    float r2[HN];
    fillp<0>(r2, plane, lane);           // cols 32..63
    trace_half<32, 0>(r2, kp + 32, mu, tr, sm);
    rep_sweep<0>(r2, r1);                // deferred right-half updates
    solo_sweep<0>(r2, logdet);           // trailing 32x32 pivots

    float contrib = tr + mu * sm;
#pragma unroll
    for (int off = 32; off >= 1; off >>= 1) contrib += __shfl_xor(contrib, off, 64);

    if (lane == 0) {
        float klp = 0.5f * (logdetK[l] - logdet - (float)TN + contrib);
        atomicAdd(&out[b], klp);
    }
}

// ======================== fused k_ll + k_kinv ==============================
// k_kinv (register-multiplier Gauss-Jordan), one wave per l, no LDS.
template<int J>
__device__ __forceinline__ void pan_load(float (&p)[HN], const float* __restrict__ Kmat,
                                         int i, int l, int jbase) {
    if constexpr (J < HN) {
        p[J] = Kmat[(i * TN + jbase + J) * LN + l];
        pan_load<J + 1>(p, Kmat, i, l, jbase);
    }
}
template<int K, int J>
__device__ __forceinline__ void ki_upd(float (&a)[HN], float c) {
    if constexpr (J < HN) {
        a[J] = fmaf(-c, bcastf(a[J], K), a[J]);
        ki_upd<K, J + 1>(a, c);
    }
}
template<int K>
__device__ __forceinline__ void ki_a1sweep(float (&a1)[HN], float& ld, float& piv, int i) {
    if constexpr (K < HN) {
        float dkk = bcastf(a1[K], K);
        ld += __logf(dkk);
        if (i == K) piv = dkk;
        float c = (i == K) ? 0.0f : a1[K] * __builtin_amdgcn_rcpf(dkk);
        ki_upd<K, K + 1>(a1, c);
        a1[K] = c;                        // multiplier -> dead slot
        ki_a1sweep<K + 1>(a1, ld, piv, i);
    }
}
template<int K>
__device__ __forceinline__ void ki_replay(float (&a2)[HN], const float (&a1)[HN]) {
    if constexpr (K < HN) {
        ki_upd<K, 0>(a2, a1[K]);          // full-width GJ replay of steps 0..31
        ki_replay<K + 1>(a2, a1);
    }
}
template<int Q, int J>
__device__ __forceinline__ void ki_upd2(float (&a2)[HN], float c) {
    if constexpr (J < HN) {
        a2[J] = fmaf(-c, bcastf(a2[J], 32 + Q), a2[J]);
        ki_upd2<Q, J + 1>(a2, c);
    }
}
template<int Q>
__device__ __forceinline__ void ki_a2sweep(float (&a2)[HN], float& ld, float& piv, int i) {
    if constexpr (Q < HN) {
        float dkk = bcastf(a2[Q], 32 + Q);
        ld += __logf(dkk);
        if (i == 32 + Q) piv = dkk;
        float c = (i == 32 + Q) ? 0.0f : a2[Q] * __builtin_amdgcn_rcpf(dkk);
        ki_upd2<Q, Q + 1>(a2, c);
        a2[Q] = c;                        // multiplier -> dead slot
        ki_a2sweep<Q + 1>(a2, ld, piv, i);
    }
}
// inverse reconstruction from stored multipliers
template<int J>
__device__ __forceinline__ void g1_init(float (&g)[HN], int i) {
    if constexpr (J < HN) { g[J] = (J == i) ? 1.0f : 0.0f; g1_init<J + 1>(g, i); }
}
template<int K, int J>
__device__ __forceinline__ void g1_updA(float (&g)[HN], float c) {
    if constexpr (J <= K) {
        g[J] = fmaf(-c, bcastf(g[J], K), g[J]);
        g1_updA<K, J + 1>(g, c);
    }
}
template<int K>
__device__ __forceinline__ void g1_phase1(float (&g)[HN], const float (&a1)[HN]) {
    if constexpr (K < HN) {
        g1_updA<K, 0>(g, a1[K]);
        g1_phase1<K + 1>(g, a1);
    }
}
template<int Q, int J>
__device__ __forceinline__ void g1_updB(float (&g)[HN], float c) {
    if constexpr (J < HN) {
        g[J] = fmaf(-c, bcastf(g[J], 32 + Q), g[J]);
        g1_updB<Q, J + 1>(g, c);
    }
}
template<int Q>
__device__ __forceinline__ void g1_phase2(float (&g)[HN], const float (&a2)[HN]) {
    if constexpr (Q < HN) {
        g1_updB<Q, 0>(g, a2[Q]);
        g1_phase2<Q + 1>(g, a2);
    }
}
template<int J>
__device__ __forceinline__ void g2_init(float (&g)[HN], int i) {
    if constexpr (J < HN) { g[J] = (32 + J == i) ? 1.0f : 0.0f; g2_init<J + 1>(g, i); }
}
template<int Q, int J>
__device__ __forceinline__ void g2_upd(float (&g)[HN], float c) {
    if constexpr (J <= Q) {
        g[J] = fmaf(-c, bcastf(g[J], 32 + Q), g[J]);
        g2_upd<Q, J + 1>(g, c);
    }
}
template<int Q>
__device__ __forceinline__ void g2_phase(float (&g)[HN], const float (&a2)[HN]) {
    if constexpr (Q < HN) {
        g2_upd<Q, 0>(g, a2[Q]);
        g2_phase<Q + 1>(g, a2);
    }
}
template<int J>
__device__ __forceinline__ void pan_out(const float (&g)[HN], float rdi,
                                        float* __restrict__ dst) {
    if constexpr (J < HN) {
        dst[J] = g[J] * rdi;
        pan_out<J + 1>(g, rdi, dst);
    }
}

// Fused launch: blocks 0..31 compute Kinv (dispatched first, hides under the
// memory-bound ll sweep); blocks 32..1055 do the log-likelihood reduction.
__global__ __launch_bounds__(256)
void k_ll_kinv(const float* __restrict__ X,
               const float* __restrict__ Mn,
               const float* __restrict__ R,
               const float* __restrict__ Kmat,
               float* __restrict__ kinv,
               float* __restrict__ logdetK,
               float* __restrict__ out) {
    if (blockIdx.x < 32) {
        // ---- Kinv for latent l, wave 0 only ----
        if (threadIdx.x >= 64) return;
        const int l = blockIdx.x;
        const int i = threadIdx.x;       // row

        float ld = 0.0f, piv = 1.0f;
        float a1[HN], a2[HN];
        pan_load<0>(a1, Kmat, i, l, 0);
        ki_a1sweep<0>(a1, ld, piv, i);   // a1 -> multipliers c_0..31
        pan_load<0>(a2, Kmat, i, l, 32);
        ki_replay<0>(a2, a1);
        ki_a2sweep<0>(a2, ld, piv, i);   // a2 -> multipliers c_32..63
        float rdi = __builtin_amdgcn_rcpf(piv);
        {
            float g2[HN];
            g2_init<0>(g2, i);
            g2_phase<0>(g2, a2);
            pan_out<0>(g2, rdi, kinv + l * (TN * TN) + i * TN + 32);
        }
        {
            float g1[HN];
            g1_init<0>(g1, i);
            g1_phase1<0>(g1, a1);
            g1_phase2<0>(g1, a2);
            pan_out<0>(g1, rdi, kinv + l * (TN * TN) + i * TN);
        }
        if (i == 0) logdetK[l] = ld;
        return;
    }

    // ---- log-likelihood block (b,s) ----
    int hw = blockIdx.x - 32;            // 1024 blocks
    int g = (hw & 7) * 128 + (hw >> 3);
    int b = g >> 2, s = g & 3;
    int tid = threadIdx.x;

    const float4* xp = (const float4*)(X + (size_t)b * TN * DN);
    const float4* mp = (const float4*)(Mn + ((size_t)(b * SN + s) * TN) * DN);

    int c = tid & 31;
    float4 rv = ((const float4*)R)[c];
    float4 ri = make_float4(1.0f / rv.x, 1.0f / rv.y, 1.0f / rv.z, 1.0f / rv.w);

    float acc = 0.0f;
#pragma unroll
    for (int it = 0; it < (TN * DN / 4) / 256; ++it) {
        int f = tid + it * 256;
        float4 xv = xp[f];
        float4 mv = mp[f];
        float dx = xv.x - mv.x; acc = fmaf(dx * dx, ri.x, acc);
        float dy = xv.y - mv.y; acc = fmaf(dy * dy, ri.y, acc);
        float dz = xv.z - mv.z; acc = fmaf(dz * dz, ri.z, acc);
        float dw = xv.w - mv.w; acc = fmaf(dw * dw, ri.w, acc);
    }
#pragma unroll
    for (int off = 32; off >= 1; off >>= 1) acc += __shfl_xor(acc, off, 64);

    __shared__ float wsum[4];
    if ((tid & 63) == 0) wsum[tid >> 6] = acc;
    __syncthreads();
    if (tid == 0) {
        float q = wsum[0] + wsum[1] + wsum[2] + wsum[3];
        float val = q * (0.5f / SN);
        if (s == 0) {
            float slr = 0.0f;
#pragma unroll
            for (int d = 0; d < DN; ++d) slr += __logf(R[d]);
            val += 0.5f * (float)TN * (slr + (float)DN * LOG2PI);
        }
        atomicAdd(&out[b], val);
    }
}

// ---------------------------------------------------------------------------
extern "C" void kernel_launch(void* const* d_in, const int* in_sizes, int n_in,
                              void* d_out, int out_size, void* d_ws, size_t ws_size,
                              hipStream_t stream) {
    const float* X   = (const float*)d_in[0];  // [B,T,D]
    const float* Mn  = (const float*)d_in[1];  // [B,S,T,D]
    const float* R   = (const float*)d_in[2];  // [D]
    const float* mus = (const float*)d_in[3];  // [B,T,L]
    const float* Sg  = (const float*)d_in[4];  // [B,T,T,L]
    const float* Km  = (const float*)d_in[5];  // [T,T,L]
    float* out = (float*)d_out;                // [B] fp32

    float* kinv = (float*)d_ws;                // 32*4096 floats = 512 KB
    float* ldK  = kinv + LN * TN * TN;         // 32 floats

    hipMemsetAsync(d_out, 0, BN * sizeof(float), stream);
    k_ll_kinv<<<32 + BN * SN, 256, 0, stream>>>(X, Mn, R, Km, kinv, ldK, out);
    k_chol<<<BN * 8, 256, 0, stream>>>(Sg, mus, kinv, ldK, out);
}